// Round 4
// baseline (341.525 us; speedup 1.0000x reference)
//
#include <hip/hip_runtime.h>

#define FD 128
#define BN_EPS 1e-5f
#define NB_SCAN 256    // max scan blocks supported (N <= 256*256)
#define BSHIFT 5       // 32 dst nodes per bucket
#define BCAP 1024      // slots per bucket (mean 512 for E=800k -> 22 sigma margin)

typedef short s8v __attribute__((ext_vector_type(8)));    // 8 bf16 bit-patterns
typedef float f4v __attribute__((ext_vector_type(4)));

__device__ __forceinline__ unsigned short f2bf(float f) {
    unsigned u = __float_as_uint(f);
    u += 0x7fff + ((u >> 16) & 1);           // RNE
    return (unsigned short)(u >> 16);
}
__device__ __forceinline__ float bf_lo(unsigned int u) {
    return __uint_as_float(u << 16);
}
__device__ __forceinline__ float bf_hi(unsigned int u) {
    return __uint_as_float(u & 0xffff0000u);
}

// ---------------------------------------------------------------------------
// Edge-index format probe (int32 vs int64), deterministic.
// ---------------------------------------------------------------------------
__global__ __launch_bounds__(256) void detect_kernel(const int* __restrict__ ei,
                                                     int n32, int* flag) {
    __shared__ int any;
    if (threadIdx.x == 0) any = 0;
    __syncthreads();
    int limit = n32 < 4096 ? n32 : 4096;
    int found = 0;
    for (int i = threadIdx.x * 2 + 1; i < limit; i += 512) {
        if (ei[i] != 0) { found = 1; break; }
    }
    if (found) atomicOr(&any, 1);
    __syncthreads();
    if (threadIdx.x == 0) flag[0] = any ? 0 : 1;   // 1 => int64 layout
}

__device__ __forceinline__ int edge_get(const void* ei, int is64, size_t idx) {
    return is64 ? (int)((const long long*)ei)[idx] : ((const int*)ei)[idx];
}

// ---------------------------------------------------------------------------
// Bucketed CSR build
// ---------------------------------------------------------------------------
__global__ __launch_bounds__(256) void zero_bcur_kernel(int* bcur, int nb) {
    int i = blockIdx.x * 256 + threadIdx.x;
    if (i < nb) bcur[i] = 0;
}

__global__ __launch_bounds__(256) void bucket_append_kernel(const void* ei, const int* flag,
                                                            int* __restrict__ bcur,
                                                            uint2* __restrict__ bbuf, int E) {
    int e = blockIdx.x * 256 + threadIdx.x;
    if (e >= E) return;
    int is64 = flag[0];
    int s = edge_get(ei, is64, e);
    int d = edge_get(ei, is64, (size_t)E + e);
    int b = d >> BSHIFT;
    int pos = atomicAdd(&bcur[b], 1);
    if (pos < BCAP) bbuf[(size_t)b * BCAP + pos] = make_uint2((unsigned)s, (unsigned)d);
}

// one block per bucket: LDS histogram -> indeg + dinv (coalesced, no global atomics)
__global__ __launch_bounds__(256) void bucket_hist_kernel(const uint2* __restrict__ bbuf,
                                                          const int* __restrict__ bcur,
                                                          int* __restrict__ indeg,
                                                          float* __restrict__ dinv, int n) {
    __shared__ int h[32];
    int b = blockIdx.x, t = threadIdx.x;
    if (t < 32) h[t] = 0;
    __syncthreads();
    int cnt = bcur[b]; if (cnt > BCAP) cnt = BCAP;
    const uint2* bb = bbuf + (size_t)b * BCAP;
    for (int i = t; i < cnt; i += 256)
        atomicAdd(&h[bb[i].y & 31], 1);
    __syncthreads();
    if (t < 32) {
        int d0 = (b << BSHIFT) + t;
        if (d0 < n) {
            indeg[d0] = h[t];
            dinv[d0] = rsqrtf(1.0f + (float)h[t]);
        }
    }
}

// per-block exclusive scan of indeg (256 elems/block)
__global__ __launch_bounds__(256) void scan1_kernel(const int* __restrict__ indeg,
                                                    int* __restrict__ rowptr,
                                                    int* __restrict__ blockSums, int n) {
    __shared__ int tmp[256];
    int t = threadIdx.x;
    int idx = blockIdx.x * 256 + t;
    int v = (idx < n) ? indeg[idx] : 0;
    tmp[t] = v;
    __syncthreads();
    for (int off = 1; off < 256; off <<= 1) {
        int x = (t >= off) ? tmp[t - off] : 0;
        __syncthreads();
        tmp[t] += x;
        __syncthreads();
    }
    if (idx < n) rowptr[idx] = tmp[t] - v;
    if (t == 255) blockSums[blockIdx.x] = tmp[255];
}

__global__ __launch_bounds__(256) void scan2_kernel(int* __restrict__ rowptr,
                                                    const int* __restrict__ blockSums,
                                                    int n, int E) {
    __shared__ int bs[NB_SCAN];
    int t = threadIdx.x;
    int nb = gridDim.x;
    bs[t] = (t < nb) ? blockSums[t] : 0;
    __syncthreads();
    int offset = 0;
    for (int j = 0; j < blockIdx.x; ++j) offset += bs[j];
    int idx = blockIdx.x * 256 + t;
    if (idx < n) rowptr[idx] += offset;
    if (blockIdx.x == 0 && t == 0) rowptr[n] = E;
}

// one block per bucket: scatter src into col at rowptr[d] + local rank
__global__ __launch_bounds__(256) void csr_fill_kernel(const uint2* __restrict__ bbuf,
                                                       const int* __restrict__ bcur,
                                                       const int* __restrict__ rowptr,
                                                       int* __restrict__ col, int n) {
    __shared__ int base[32];
    __shared__ int cur[32];
    int b = blockIdx.x, t = threadIdx.x;
    if (t < 32) {
        int d0 = (b << BSHIFT) + t;
        base[t] = (d0 < n) ? rowptr[d0] : 0;
        cur[t] = 0;
    }
    __syncthreads();
    int cnt = bcur[b]; if (cnt > BCAP) cnt = BCAP;
    const uint2* bb = bbuf + (size_t)b * BCAP;
    for (int i = t; i < cnt; i += 256) {
        uint2 e = bb[i];
        int dl = e.y & 31;
        int r = atomicAdd(&cur[dl], 1);
        col[base[dl] + r] = (int)e.x;
    }
}

// ---------------------------------------------------------------------------
// W[128,128] f32 -> fragment-ordered bf16 for mfma_f32_16x16x32_bf16 B-operand.
// ---------------------------------------------------------------------------
__global__ __launch_bounds__(256) void wprep_kernel(const float* __restrict__ W,
                                                    unsigned short* __restrict__ Wfrag) {
    int idx = blockIdx.x * 256 + threadIdx.x;   // 16384 total
    int j = idx & 7, lane = (idx >> 3) & 63, ct = (idx >> 9) & 7, kt = idx >> 12;
    int k = kt * 32 + (lane >> 4) * 8 + j;
    int c = ct * 16 + (lane & 15);
    Wfrag[idx] = f2bf(W[k * FD + c]);
}

// ---------------------------------------------------------------------------
// C[n,128] = (A[n,128] @ W) * dinv[row], stored bf16.
// ---------------------------------------------------------------------------
template<int IN_BF16>
__global__ __launch_bounds__(256) void gemm_mfma_kernel(const void* __restrict__ Ain,
                                                        const unsigned short* __restrict__ Wfrag,
                                                        const float* __restrict__ dinv,
                                                        unsigned short* __restrict__ C,
                                                        int n) {
    int wave = threadIdx.x >> 6, lane = threadIdx.x & 63;
    int rbase = blockIdx.x * 64 + wave * 16;
    int lrow = rbase + (lane & 15);
    int kg = lane >> 4;
    bool rok = lrow < n;

    f4v acc[8];
#pragma unroll
    for (int i = 0; i < 8; ++i) acc[i] = (f4v){0.f, 0.f, 0.f, 0.f};

    const s8v* wf = (const s8v*)Wfrag;

#pragma unroll
    for (int kt = 0; kt < 4; ++kt) {
        s8v afr = (s8v){0, 0, 0, 0, 0, 0, 0, 0};
        if (rok) {
            if (IN_BF16) {
                const unsigned short* A = (const unsigned short*)Ain;
                afr = *(const s8v*)(A + (size_t)lrow * FD + kt * 32 + kg * 8);
            } else {
                const float* A = (const float*)Ain;
                const float* p = A + (size_t)lrow * FD + kt * 32 + kg * 8;
                float4 u0 = *(const float4*)p;
                float4 u1 = *(const float4*)(p + 4);
                afr[0] = (short)f2bf(u0.x); afr[1] = (short)f2bf(u0.y);
                afr[2] = (short)f2bf(u0.z); afr[3] = (short)f2bf(u0.w);
                afr[4] = (short)f2bf(u1.x); afr[5] = (short)f2bf(u1.y);
                afr[6] = (short)f2bf(u1.z); afr[7] = (short)f2bf(u1.w);
            }
        }
#pragma unroll
        for (int ct = 0; ct < 8; ++ct) {
            s8v bfr = wf[(kt * 8 + ct) * 64 + lane];
            acc[ct] = __builtin_amdgcn_mfma_f32_16x16x32_bf16(afr, bfr, acc[ct], 0, 0, 0);
        }
    }

    int col0 = lane & 15;
#pragma unroll
    for (int r = 0; r < 4; ++r) {
        int row = rbase + kg * 4 + r;
        if (row < n) {
            float dv = dinv[row];
            unsigned short* crow = C + (size_t)row * FD;
#pragma unroll
            for (int ct = 0; ct < 8; ++ct)
                crow[ct * 16 + col0] = f2bf(acc[ct][r] * dv);
        }
    }
}

// ---------------------------------------------------------------------------
// CSR gather: one wave per dst node, 2 bf16 per lane.
// ---------------------------------------------------------------------------
__global__ __launch_bounds__(256) void gather_kernel(const unsigned int* __restrict__ hs,
                                                     const int* __restrict__ rowptr,
                                                     const int* __restrict__ col,
                                                     const float* __restrict__ dinv,
                                                     const float* __restrict__ b,
                                                     float* __restrict__ agg, int n) {
    int wid = (blockIdx.x * 256 + threadIdx.x) >> 6;
    int lane = threadIdx.x & 63;
    if (wid >= n) return;
    float dv = dinv[wid];
    size_t base = (size_t)wid * 64 + lane;
    unsigned int u = hs[base];                 // self term
    float ax = bf_lo(u), ay = bf_hi(u);
    int i = rowptr[wid], end = rowptr[wid + 1];
    for (; i + 4 <= end; i += 4) {
        int s0 = col[i], s1 = col[i + 1], s2 = col[i + 2], s3 = col[i + 3];
        unsigned int v0 = hs[(size_t)s0 * 64 + lane];
        unsigned int v1 = hs[(size_t)s1 * 64 + lane];
        unsigned int v2 = hs[(size_t)s2 * 64 + lane];
        unsigned int v3 = hs[(size_t)s3 * 64 + lane];
        ax += bf_lo(v0) + bf_lo(v1) + bf_lo(v2) + bf_lo(v3);
        ay += bf_hi(v0) + bf_hi(v1) + bf_hi(v2) + bf_hi(v3);
    }
    for (; i < end; ++i) {
        unsigned int v = hs[(size_t)col[i] * 64 + lane];
        ax += bf_lo(v);
        ay += bf_hi(v);
    }
    float2 bb = ((const float2*)b)[lane];
    float2 o;
    o.x = dv * ax + bb.x;
    o.y = dv * ay + bb.y;
    ((float2*)agg)[base] = o;
}

// ---------------------------------------------------------------------------
// BatchNorm + PReLU
// ---------------------------------------------------------------------------
__global__ __launch_bounds__(256) void zero_stats_kernel(float* stats) {
    stats[threadIdx.x] = 0.0f;
}

__global__ __launch_bounds__(256) void bn_stats_kernel(const float* __restrict__ agg,
                                                       float* __restrict__ stats, int n) {
    int tid = threadIdx.x;
    int c = tid & 127;
    int r0 = blockIdx.x * 2 + (tid >> 7);
    int stride = gridDim.x * 2;
    float s = 0.f, ss = 0.f;
    for (int r = r0; r < n; r += stride) {
        float v = agg[(size_t)r * FD + c];
        s += v; ss += v * v;
    }
    atomicAdd(&stats[c], s);
    atomicAdd(&stats[FD + c], ss);
}

__global__ __launch_bounds__(128) void bn_finalize_kernel(float* stats,
                                                          const float* __restrict__ g,
                                                          const float* __restrict__ be,
                                                          float invn) {
    int c = threadIdx.x;
    float mu = stats[c] * invn;
    float var = stats[FD + c] * invn - mu * mu;
    float sc = g[c] * rsqrtf(var + BN_EPS);
    stats[2 * FD + c] = sc;
    stats[3 * FD + c] = be[c] - mu * sc;
}

template<int OUT_BF16>
__global__ __launch_bounds__(256) void bn_apply_kernel(const float* __restrict__ agg,
                                                       const float* __restrict__ stats,
                                                       const float* __restrict__ aP,
                                                       void* __restrict__ out, int n) {
    int t = blockIdx.x * 256 + threadIdx.x;
    if (t >= n * (FD / 4)) return;
    int c4 = t & 31;
    float alpha = aP[0];
    float4 v = ((const float4*)agg)[t];
    float4 sc = ((const float4*)(stats + 2 * FD))[c4];
    float4 sh = ((const float4*)(stats + 3 * FD))[c4];
    float4 y;
    y.x = v.x * sc.x + sh.x; y.y = v.y * sc.y + sh.y;
    y.z = v.z * sc.z + sh.z; y.w = v.w * sc.w + sh.w;
    y.x = y.x >= 0.f ? y.x : alpha * y.x;
    y.y = y.y >= 0.f ? y.y : alpha * y.y;
    y.z = y.z >= 0.f ? y.z : alpha * y.z;
    y.w = y.w >= 0.f ? y.w : alpha * y.w;
    if (OUT_BF16) {
        uint2 p;
        p.x = (unsigned)f2bf(y.x) | ((unsigned)f2bf(y.y) << 16);
        p.y = (unsigned)f2bf(y.z) | ((unsigned)f2bf(y.w) << 16);
        ((uint2*)out)[t] = p;
    } else {
        ((float4*)out)[t] = y;
    }
}

// ---------------------------------------------------------------------------

extern "C" void kernel_launch(void* const* d_in, const int* in_sizes, int n_in,
                              void* d_out, int out_size, void* d_ws, size_t ws_size,
                              hipStream_t stream) {
    const float* x  = (const float*)d_in[0];
    const void*  ei = d_in[1];
    const float* W1 = (const float*)d_in[2];
    const float* b1 = (const float*)d_in[3];
    const float* g1 = (const float*)d_in[4];
    const float* be1= (const float*)d_in[5];
    const float* a1 = (const float*)d_in[6];
    const float* W2 = (const float*)d_in[7];
    const float* b2 = (const float*)d_in[8];
    const float* g2 = (const float*)d_in[9];
    const float* be2= (const float*)d_in[10];
    const float* a2 = (const float*)d_in[11];

    int N = in_sizes[0] / FD;
    int E = in_sizes[1] / 2;
    float* out = (float*)d_out;

    int nbuck = (N + (1 << BSHIFT) - 1) >> BSHIFT;

    char* ws = (char*)d_ws;
    size_t off = 0;
    auto alloc = [&](size_t bytes) {
        void* p = ws + off;
        off += (bytes + 255) & ~(size_t)255;
        return p;
    };
    float* dinv    = (float*)alloc((size_t)N * 4);
    float* stats   = (float*)alloc(512 * 4);
    int*   flag    = (int*)alloc(256);
    int*   indeg   = (int*)alloc((size_t)N * 4);
    int*   rowptr  = (int*)alloc(((size_t)N + 1) * 4);
    int*   bsums   = (int*)alloc(NB_SCAN * 4);
    int*   bcur    = (int*)alloc((size_t)nbuck * 4);
    uint2* bbuf    = (uint2*)alloc((size_t)nbuck * BCAP * 8);
    int*   colA    = (int*)alloc((size_t)E * 4);
    unsigned short* wf1 = (unsigned short*)alloc((size_t)FD * FD * 2);
    unsigned short* wf2 = (unsigned short*)alloc((size_t)FD * FD * 2);
    unsigned short* hs  = (unsigned short*)alloc((size_t)N * FD * 2);
    unsigned short* y1  = (unsigned short*)alloc((size_t)N * FD * 2);
    float* agg     = (float*)alloc((size_t)N * FD * 4);
    (void)ws_size; (void)n_in; (void)out_size;

    int nbN = (N + 255) / 256;
    int nbE = (E + 255) / 256;

    detect_kernel<<<1, 256, 0, stream>>>((const int*)ei, 2 * E, flag);

    // bucketed CSR build (once; reused by both layers)
    zero_bcur_kernel<<<(nbuck + 255) / 256, 256, 0, stream>>>(bcur, nbuck);
    bucket_append_kernel<<<nbE, 256, 0, stream>>>(ei, flag, bcur, bbuf, E);
    bucket_hist_kernel<<<nbuck, 256, 0, stream>>>(bbuf, bcur, indeg, dinv, N);
    scan1_kernel<<<nbN, 256, 0, stream>>>(indeg, rowptr, bsums, N);
    scan2_kernel<<<nbN, 256, 0, stream>>>(rowptr, bsums, N, E);
    csr_fill_kernel<<<nbuck, 256, 0, stream>>>(bbuf, bcur, rowptr, colA, N);

    // weight fragment prep
    wprep_kernel<<<64, 256, 0, stream>>>(W1, wf1);
    wprep_kernel<<<64, 256, 0, stream>>>(W2, wf2);

    int gemm_blocks = (N + 63) / 64;
    int nt = N * (FD / 4);

    // ---- layer 1 ----
    gemm_mfma_kernel<0><<<gemm_blocks, 256, 0, stream>>>(x, wf1, dinv, hs, N);
    gather_kernel<<<(N * 64 + 255) / 256, 256, 0, stream>>>((const unsigned int*)hs,
                                                            rowptr, colA, dinv, b1, agg, N);
    zero_stats_kernel<<<1, 256, 0, stream>>>(stats);
    bn_stats_kernel<<<400, 256, 0, stream>>>(agg, stats, N);
    bn_finalize_kernel<<<1, 128, 0, stream>>>(stats, g1, be1, 1.0f / (float)N);
    bn_apply_kernel<1><<<(nt + 255) / 256, 256, 0, stream>>>(agg, stats, a1, y1, N);

    // ---- layer 2 ----
    gemm_mfma_kernel<1><<<gemm_blocks, 256, 0, stream>>>(y1, wf2, dinv, hs, N);
    gather_kernel<<<(N * 64 + 255) / 256, 256, 0, stream>>>((const unsigned int*)hs,
                                                            rowptr, colA, dinv, b2, agg, N);
    zero_stats_kernel<<<1, 256, 0, stream>>>(stats);
    bn_stats_kernel<<<400, 256, 0, stream>>>(agg, stats, N);
    bn_finalize_kernel<<<1, 128, 0, stream>>>(stats, g2, be2, 1.0f / (float)N);
    bn_apply_kernel<0><<<(nt + 255) / 256, 256, 0, stream>>>(agg, stats, a2, out, N);
}

// Round 5
// 241.396 us; speedup vs baseline: 1.4148x; 1.4148x over previous
//
#include <hip/hip_runtime.h>

#define FD 128
#define BN_EPS 1e-5f
#define BSH 8          // 256 dst nodes per bucket  (requires N <= 65536)
#define CAP 6144       // slots per bucket (mean 4082 for E=800k -> +32 sigma)
#define BE 8192        // edges per partition block

typedef short s8v __attribute__((ext_vector_type(8)));    // 8 bf16 bit-patterns
typedef float f4v __attribute__((ext_vector_type(4)));

__device__ __forceinline__ unsigned short f2bf(float f) {
    unsigned u = __float_as_uint(f);
    u += 0x7fff + ((u >> 16) & 1);           // RNE
    return (unsigned short)(u >> 16);
}
__device__ __forceinline__ float bf_lo(unsigned int u) {
    return __uint_as_float(u << 16);
}
__device__ __forceinline__ float bf_hi(unsigned int u) {
    return __uint_as_float(u & 0xffff0000u);
}

// ---------------------------------------------------------------------------
// Edge-index format probe (int32 vs int64) + zero bucket cursors.
// ---------------------------------------------------------------------------
__global__ __launch_bounds__(256) void detect_kernel(const int* __restrict__ ei,
                                                     int n32, int* flag, int* gcur) {
    __shared__ int any;
    gcur[threadIdx.x] = 0;
    if (threadIdx.x == 0) any = 0;
    __syncthreads();
    int limit = n32 < 4096 ? n32 : 4096;
    int found = 0;
    for (int i = threadIdx.x * 2 + 1; i < limit; i += 512) {
        if (ei[i] != 0) { found = 1; break; }
    }
    if (found) atomicOr(&any, 1);
    __syncthreads();
    if (threadIdx.x == 0) flag[0] = any ? 0 : 1;   // 1 => int64 layout
}

__device__ __forceinline__ int edge_get(const void* ei, int is64, size_t idx) {
    return is64 ? (int)((const long long*)ei)[idx] : ((const int*)ei)[idx];
}

// ---------------------------------------------------------------------------
// Phase 1: partition edges into 256-node dst-range buckets.
// Packed entry: src | (dst&255)<<24   (requires src < 2^24)
// ---------------------------------------------------------------------------
__global__ __launch_bounds__(256) void partition_kernel(const void* ei, const int* flag,
                                                        int* __restrict__ gcur,
                                                        unsigned* __restrict__ slab, int E) {
    __shared__ int hist[256];
    __shared__ int base[256];
    __shared__ int cur[256];
    int t = threadIdx.x;
    int e0 = blockIdx.x * BE;
    int cnt = E - e0; if (cnt > BE) cnt = BE;
    hist[t] = 0;
    __syncthreads();
    int is64 = flag[0];
    for (int i = t; i < cnt; i += 256) {
        int d = edge_get(ei, is64, (size_t)E + e0 + i);
        atomicAdd(&hist[d >> BSH], 1);
    }
    __syncthreads();
    base[t] = hist[t] ? atomicAdd(&gcur[t], hist[t]) : 0;
    cur[t] = 0;
    __syncthreads();
    for (int i = t; i < cnt; i += 256) {
        int s = edge_get(ei, is64, e0 + i);
        int d = edge_get(ei, is64, (size_t)E + e0 + i);
        int b = d >> BSH;
        int r = atomicAdd(&cur[b], 1);
        int pos = base[b] + r;
        if (pos < CAP)
            slab[(size_t)b * CAP + pos] = (unsigned)s | ((unsigned)(d & 255) << 24);
    }
}

// ---------------------------------------------------------------------------
// Phase 2: one block per bucket -> dst-sorted colslab + nodeptr(start,cnt) + dinv.
// ---------------------------------------------------------------------------
__global__ __launch_bounds__(256) void bucket_csr_kernel(const unsigned* __restrict__ slab,
                                                         const int* __restrict__ gcur,
                                                         int* __restrict__ colslab,
                                                         uint2* __restrict__ nodeptr,
                                                         float* __restrict__ dinv, int n) {
    __shared__ int hist[256];
    __shared__ int loc[256];
    __shared__ int cur[256];
    __shared__ int tmp[256];
    int b = blockIdx.x, t = threadIdx.x;
    hist[t] = 0;
    __syncthreads();
    int cnt = gcur[b]; if (cnt > CAP) cnt = CAP;
    const unsigned* sl = slab + (size_t)b * CAP;
    for (int i = t; i < cnt; i += 256)
        atomicAdd(&hist[sl[i] >> 24], 1);
    __syncthreads();
    int v = hist[t];
    tmp[t] = v;
    __syncthreads();
    for (int off = 1; off < 256; off <<= 1) {
        int x = (t >= off) ? tmp[t - off] : 0;
        __syncthreads();
        tmp[t] += x;
        __syncthreads();
    }
    int start_loc = tmp[t] - v;              // exclusive prefix
    loc[t] = start_loc;
    cur[t] = 0;
    int node = (b << BSH) + t;
    if (node < n) {
        dinv[node] = rsqrtf(1.0f + (float)v);
        nodeptr[node] = make_uint2((unsigned)(b * CAP + start_loc), (unsigned)v);
    }
    __syncthreads();
    for (int i = t; i < cnt; i += 256) {
        unsigned e = sl[i];
        int dl = e >> 24;
        int r = atomicAdd(&cur[dl], 1);
        colslab[(size_t)b * CAP + loc[dl] + r] = (int)(e & 0xFFFFFF);
    }
}

// ---------------------------------------------------------------------------
// W[128,128] f32 -> fragment-ordered bf16 for mfma_f32_16x16x32_bf16 B-operand.
// ---------------------------------------------------------------------------
__global__ __launch_bounds__(256) void wprep_kernel(const float* __restrict__ W,
                                                    unsigned short* __restrict__ Wfrag) {
    int idx = blockIdx.x * 256 + threadIdx.x;   // 16384 total
    int j = idx & 7, lane = (idx >> 3) & 63, ct = (idx >> 9) & 7, kt = idx >> 12;
    int k = kt * 32 + (lane >> 4) * 8 + j;
    int c = ct * 16 + (lane & 15);
    Wfrag[idx] = f2bf(W[k * FD + c]);
}

// ---------------------------------------------------------------------------
// C[n,128] = (A[n,128] @ W) * dinv[row], stored bf16.
// ---------------------------------------------------------------------------
template<int IN_BF16>
__global__ __launch_bounds__(256) void gemm_mfma_kernel(const void* __restrict__ Ain,
                                                        const unsigned short* __restrict__ Wfrag,
                                                        const float* __restrict__ dinv,
                                                        unsigned short* __restrict__ C,
                                                        int n) {
    int wave = threadIdx.x >> 6, lane = threadIdx.x & 63;
    int rbase = blockIdx.x * 64 + wave * 16;
    int lrow = rbase + (lane & 15);
    int kg = lane >> 4;
    bool rok = lrow < n;

    f4v acc[8];
#pragma unroll
    for (int i = 0; i < 8; ++i) acc[i] = (f4v){0.f, 0.f, 0.f, 0.f};

    const s8v* wf = (const s8v*)Wfrag;

#pragma unroll
    for (int kt = 0; kt < 4; ++kt) {
        s8v afr = (s8v){0, 0, 0, 0, 0, 0, 0, 0};
        if (rok) {
            if (IN_BF16) {
                const unsigned short* A = (const unsigned short*)Ain;
                afr = *(const s8v*)(A + (size_t)lrow * FD + kt * 32 + kg * 8);
            } else {
                const float* A = (const float*)Ain;
                const float* p = A + (size_t)lrow * FD + kt * 32 + kg * 8;
                float4 u0 = *(const float4*)p;
                float4 u1 = *(const float4*)(p + 4);
                afr[0] = (short)f2bf(u0.x); afr[1] = (short)f2bf(u0.y);
                afr[2] = (short)f2bf(u0.z); afr[3] = (short)f2bf(u0.w);
                afr[4] = (short)f2bf(u1.x); afr[5] = (short)f2bf(u1.y);
                afr[6] = (short)f2bf(u1.z); afr[7] = (short)f2bf(u1.w);
            }
        }
#pragma unroll
        for (int ct = 0; ct < 8; ++ct) {
            s8v bfr = wf[(kt * 8 + ct) * 64 + lane];
            acc[ct] = __builtin_amdgcn_mfma_f32_16x16x32_bf16(afr, bfr, acc[ct], 0, 0, 0);
        }
    }

    int col0 = lane & 15;
#pragma unroll
    for (int r = 0; r < 4; ++r) {
        int row = rbase + kg * 4 + r;
        if (row < n) {
            float dv = dinv[row];
            unsigned short* crow = C + (size_t)row * FD;
#pragma unroll
            for (int ct = 0; ct < 8; ++ct)
                crow[ct * 16 + col0] = f2bf(acc[ct][r] * dv);
        }
    }
}

// ---------------------------------------------------------------------------
// CSR gather: one wave per dst node, 2 bf16 per lane.
// agg[d] = dinv[d]*( sum_{s in N(d)} hs[s] + hs[d] ) + bias
// ---------------------------------------------------------------------------
__global__ __launch_bounds__(256) void gather_kernel(const unsigned int* __restrict__ hs,
                                                     const uint2* __restrict__ nodeptr,
                                                     const int* __restrict__ col,
                                                     const float* __restrict__ dinv,
                                                     const float* __restrict__ b,
                                                     float* __restrict__ agg, int n) {
    int wid = (blockIdx.x * 256 + threadIdx.x) >> 6;
    int lane = threadIdx.x & 63;
    if (wid >= n) return;
    float dv = dinv[wid];
    size_t base = (size_t)wid * 64 + lane;
    unsigned int u = hs[base];                 // self term
    float ax = bf_lo(u), ay = bf_hi(u);
    uint2 p = nodeptr[wid];
    int i = (int)p.x, end = (int)(p.x + p.y);
    for (; i + 4 <= end; i += 4) {
        int s0 = col[i], s1 = col[i + 1], s2 = col[i + 2], s3 = col[i + 3];
        unsigned int v0 = hs[(size_t)s0 * 64 + lane];
        unsigned int v1 = hs[(size_t)s1 * 64 + lane];
        unsigned int v2 = hs[(size_t)s2 * 64 + lane];
        unsigned int v3 = hs[(size_t)s3 * 64 + lane];
        ax += bf_lo(v0) + bf_lo(v1) + bf_lo(v2) + bf_lo(v3);
        ay += bf_hi(v0) + bf_hi(v1) + bf_hi(v2) + bf_hi(v3);
    }
    for (; i < end; ++i) {
        unsigned int v = hs[(size_t)col[i] * 64 + lane];
        ax += bf_lo(v);
        ay += bf_hi(v);
    }
    float2 bb = ((const float2*)b)[lane];
    float2 o;
    o.x = dv * ax + bb.x;
    o.y = dv * ay + bb.y;
    ((float2*)agg)[base] = o;
}

// ---------------------------------------------------------------------------
// BatchNorm + PReLU
// ---------------------------------------------------------------------------
__global__ __launch_bounds__(256) void zero_stats_kernel(float* stats) {
    stats[threadIdx.x] = 0.0f;
}

__global__ __launch_bounds__(256) void bn_stats_kernel(const float* __restrict__ agg,
                                                       float* __restrict__ stats, int n) {
    int tid = threadIdx.x;
    int c = tid & 127;
    int r0 = blockIdx.x * 2 + (tid >> 7);
    int stride = gridDim.x * 2;
    float s = 0.f, ss = 0.f;
    for (int r = r0; r < n; r += stride) {
        float v = agg[(size_t)r * FD + c];
        s += v; ss += v * v;
    }
    atomicAdd(&stats[c], s);
    atomicAdd(&stats[FD + c], ss);
}

__global__ __launch_bounds__(128) void bn_finalize_kernel(float* stats,
                                                          const float* __restrict__ g,
                                                          const float* __restrict__ be,
                                                          float invn) {
    int c = threadIdx.x;
    float mu = stats[c] * invn;
    float var = stats[FD + c] * invn - mu * mu;
    float sc = g[c] * rsqrtf(var + BN_EPS);
    stats[2 * FD + c] = sc;
    stats[3 * FD + c] = be[c] - mu * sc;
}

template<int OUT_BF16>
__global__ __launch_bounds__(256) void bn_apply_kernel(const float* __restrict__ agg,
                                                       const float* __restrict__ stats,
                                                       const float* __restrict__ aP,
                                                       void* __restrict__ out, int n) {
    int t = blockIdx.x * 256 + threadIdx.x;
    if (t >= n * (FD / 4)) return;
    int c4 = t & 31;
    float alpha = aP[0];
    float4 v = ((const float4*)agg)[t];
    float4 sc = ((const float4*)(stats + 2 * FD))[c4];
    float4 sh = ((const float4*)(stats + 3 * FD))[c4];
    float4 y;
    y.x = v.x * sc.x + sh.x; y.y = v.y * sc.y + sh.y;
    y.z = v.z * sc.z + sh.z; y.w = v.w * sc.w + sh.w;
    y.x = y.x >= 0.f ? y.x : alpha * y.x;
    y.y = y.y >= 0.f ? y.y : alpha * y.y;
    y.z = y.z >= 0.f ? y.z : alpha * y.z;
    y.w = y.w >= 0.f ? y.w : alpha * y.w;
    if (OUT_BF16) {
        uint2 p;
        p.x = (unsigned)f2bf(y.x) | ((unsigned)f2bf(y.y) << 16);
        p.y = (unsigned)f2bf(y.z) | ((unsigned)f2bf(y.w) << 16);
        ((uint2*)out)[t] = p;
    } else {
        ((float4*)out)[t] = y;
    }
}

// ---------------------------------------------------------------------------

extern "C" void kernel_launch(void* const* d_in, const int* in_sizes, int n_in,
                              void* d_out, int out_size, void* d_ws, size_t ws_size,
                              hipStream_t stream) {
    const float* x  = (const float*)d_in[0];
    const void*  ei = d_in[1];
    const float* W1 = (const float*)d_in[2];
    const float* b1 = (const float*)d_in[3];
    const float* g1 = (const float*)d_in[4];
    const float* be1= (const float*)d_in[5];
    const float* a1 = (const float*)d_in[6];
    const float* W2 = (const float*)d_in[7];
    const float* b2 = (const float*)d_in[8];
    const float* g2 = (const float*)d_in[9];
    const float* be2= (const float*)d_in[10];
    const float* a2 = (const float*)d_in[11];

    int N = in_sizes[0] / FD;
    int E = in_sizes[1] / 2;
    float* out = (float*)d_out;

    int nbuck = (N + (1 << BSH) - 1) >> BSH;   // 196 for N=50000 (<=256 required)

    char* ws = (char*)d_ws;
    size_t off = 0;
    auto alloc = [&](size_t bytes) {
        void* p = ws + off;
        off += (bytes + 255) & ~(size_t)255;
        return p;
    };
    float* dinv    = (float*)alloc((size_t)N * 4);
    float* stats   = (float*)alloc(512 * 4);
    int*   flag    = (int*)alloc(256);
    int*   gcur    = (int*)alloc(256 * 4);
    uint2* nodeptr = (uint2*)alloc((size_t)N * 8);
    unsigned* slab = (unsigned*)alloc((size_t)nbuck * CAP * 4);
    int*   colslab = (int*)alloc((size_t)nbuck * CAP * 4);
    unsigned short* wf1 = (unsigned short*)alloc((size_t)FD * FD * 2);
    unsigned short* wf2 = (unsigned short*)alloc((size_t)FD * FD * 2);
    unsigned short* hs  = (unsigned short*)alloc((size_t)N * FD * 2);
    unsigned short* y1  = (unsigned short*)alloc((size_t)N * FD * 2);
    float* agg     = (float*)alloc((size_t)N * FD * 4);
    (void)ws_size; (void)n_in; (void)out_size;

    detect_kernel<<<1, 256, 0, stream>>>((const int*)ei, 2 * E, flag, gcur);

    // CSR build (once; reused by both layers)
    partition_kernel<<<(E + BE - 1) / BE, 256, 0, stream>>>(ei, flag, gcur, slab, E);
    bucket_csr_kernel<<<nbuck, 256, 0, stream>>>(slab, gcur, colslab, nodeptr, dinv, N);

    // weight fragment prep
    wprep_kernel<<<64, 256, 0, stream>>>(W1, wf1);
    wprep_kernel<<<64, 256, 0, stream>>>(W2, wf2);

    int gemm_blocks = (N + 63) / 64;
    int nt = N * (FD / 4);

    // ---- layer 1 ----
    gemm_mfma_kernel<0><<<gemm_blocks, 256, 0, stream>>>(x, wf1, dinv, hs, N);
    gather_kernel<<<(N * 64 + 255) / 256, 256, 0, stream>>>((const unsigned int*)hs,
                                                            nodeptr, colslab, dinv, b1, agg, N);
    zero_stats_kernel<<<1, 256, 0, stream>>>(stats);
    bn_stats_kernel<<<400, 256, 0, stream>>>(agg, stats, N);
    bn_finalize_kernel<<<1, 128, 0, stream>>>(stats, g1, be1, 1.0f / (float)N);
    bn_apply_kernel<1><<<(nt + 255) / 256, 256, 0, stream>>>(agg, stats, a1, y1, N);

    // ---- layer 2 ----
    gemm_mfma_kernel<1><<<gemm_blocks, 256, 0, stream>>>(y1, wf2, dinv, hs, N);
    gather_kernel<<<(N * 64 + 255) / 256, 256, 0, stream>>>((const unsigned int*)hs,
                                                            nodeptr, colslab, dinv, b2, agg, N);
    zero_stats_kernel<<<1, 256, 0, stream>>>(stats);
    bn_stats_kernel<<<400, 256, 0, stream>>>(agg, stats, N);
    bn_finalize_kernel<<<1, 128, 0, stream>>>(stats, g2, be2, 1.0f / (float)N);
    bn_apply_kernel<0><<<(nt + 255) / 256, 256, 0, stream>>>(agg, stats, a2, out, N);
}